// Round 1
// baseline (1234.454 us; speedup 1.0000x reference)
//
#include <hip/hip_runtime.h>
#include <cstdint>
#include <cstddef>

// Problem constants (B=4,S=2048,H=1024,F=4096,E=8,K=2)
#define T_TOK 8192
#define HD 1024
#define FD 4096
#define NE 8
#define RCAP 17408   // 16384 pairs + 8*128 padding headroom

typedef __bf16 bf16_t;
typedef __bf16 bf16x8 __attribute__((ext_vector_type(8)));
typedef __bf16 bf16x4 __attribute__((ext_vector_type(4)));
typedef float floatx4 __attribute__((ext_vector_type(4)));

#define BM 128
#define BN 128
#define BK 64
#define LDS_STRIDE 72   // BK + 8 bf16 pad: rows land 2-way on banks (free)

__device__ __forceinline__ float gelu_tanh(float x) {
    // jax.nn.gelu default (approximate=True)
    float x3 = x * x * x;
    float t = tanhf(0.7978845608028654f * (x + 0.044715f * x3));
    return 0.5f * x * (1.0f + t);
}

// ---------------------------------------------------------------------------
// Transpose + fp32->bf16 convert: in [E][R][C] fp32  ->  out [E][C][R] bf16
// grid (C/32, R/32, E), block 256
// ---------------------------------------------------------------------------
__global__ __launch_bounds__(256) void transpose_conv_kernel(
    const float* __restrict__ in, bf16_t* __restrict__ out, int R, int C)
{
    __shared__ float tile[32][33];
    const int e = blockIdx.z;
    const int c0 = blockIdx.x * 32;
    const int r0 = blockIdx.y * 32;
    const float* src = in + (size_t)e * R * C;
    bf16_t* dst = out + (size_t)e * R * C;
    const int tx = threadIdx.x & 31;
    const int ty = threadIdx.x >> 5;   // 0..7
    #pragma unroll
    for (int i = ty; i < 32; i += 8)
        tile[i][tx] = src[(size_t)(r0 + i) * C + c0 + tx];
    __syncthreads();
    #pragma unroll
    for (int i = ty; i < 32; i += 8)
        dst[(size_t)(c0 + i) * R + r0 + tx] = (bf16_t)tile[tx][i];
}

// ---------------------------------------------------------------------------
// Router: one wave per token. fp32 logits, softmax -> top2 -> renormalize.
// grid T/4, block 256
// ---------------------------------------------------------------------------
__global__ __launch_bounds__(256) void router_kernel(
    const float* __restrict__ x, const float* __restrict__ rw,
    const float* __restrict__ rb,
    int* __restrict__ tok_e, float* __restrict__ tok_w, int* __restrict__ counts)
{
    const int t = blockIdx.x * 4 + (threadIdx.x >> 6);
    const int lane = threadIdx.x & 63;
    const float* xr = x + (size_t)t * HD;
    float acc[NE];
    #pragma unroll
    for (int e = 0; e < NE; ++e) acc[e] = 0.f;
    #pragma unroll 4
    for (int i = 0; i < HD / 64; ++i) {
        int h = lane + 64 * i;
        float xv = xr[h];
        const float4* w4 = (const float4*)(rw + (size_t)h * NE);
        float4 wa = w4[0], wb = w4[1];
        acc[0] += xv * wa.x; acc[1] += xv * wa.y;
        acc[2] += xv * wa.z; acc[3] += xv * wa.w;
        acc[4] += xv * wb.x; acc[5] += xv * wb.y;
        acc[6] += xv * wb.z; acc[7] += xv * wb.w;
    }
    #pragma unroll
    for (int s = 32; s > 0; s >>= 1)
        #pragma unroll
        for (int e = 0; e < NE; ++e)
            acc[e] += __shfl_xor(acc[e], s, 64);
    if (lane == 0) {
        float l[NE];
        #pragma unroll
        for (int e = 0; e < NE; ++e) l[e] = acc[e] + rb[e];
        // top-2 on logits (same order as probs); strict > keeps first index on ties
        int e1 = 0;
        #pragma unroll
        for (int e = 1; e < NE; ++e) if (l[e] > l[e1]) e1 = e;
        int e2 = (e1 == 0) ? 1 : 0;
        #pragma unroll
        for (int e = 0; e < NE; ++e) {
            if (e == e1 || e == e2) continue;
            if (l[e] > l[e2]) e2 = e;
        }
        // renormalized top-2 weights: softmax denom cancels -> q1/(q1+q2)
        float m = l[e1];
        float q1 = 1.0f;
        float q2 = expf(l[e2] - m);
        float inv = 1.0f / (q1 + q2);
        tok_e[t * 2]     = e1;
        tok_e[t * 2 + 1] = e2;
        tok_w[t * 2]     = q1 * inv;
        tok_w[t * 2 + 1] = q2 * inv;
        atomicAdd(&counts[e1], 1);
        atomicAdd(&counts[e2], 1);
    }
}

// ---------------------------------------------------------------------------
// Offsets: prefix sum of counts padded to BM. grid 1, block 64
// ---------------------------------------------------------------------------
__global__ void offsets_kernel(const int* __restrict__ counts,
                               int* __restrict__ offsets, int* __restrict__ cursors)
{
    if (threadIdx.x == 0) {
        int cum = 0;
        for (int e = 0; e < NE; ++e) {
            offsets[e] = cum;
            cursors[e] = cum;
            cum += (counts[e] + BM - 1) & ~(BM - 1);
        }
    }
}

// ---------------------------------------------------------------------------
// Gather: one wave per (token, k) pair. Copies x row -> bf16 Xg row, records
// (token, weight). grid pairs/4, block 256
// ---------------------------------------------------------------------------
__global__ __launch_bounds__(256) void gather_kernel(
    const float* __restrict__ x, const int* __restrict__ tok_e,
    const float* __restrict__ tok_w, int* __restrict__ cursors,
    bf16_t* __restrict__ Xg, int* __restrict__ rows_token, float* __restrict__ rows_w)
{
    const int pair = blockIdx.x * 4 + (threadIdx.x >> 6);
    const int lane = threadIdx.x & 63;
    const int t = pair >> 1;
    int pos;
    if (lane == 0) {
        int e = tok_e[pair];
        pos = atomicAdd(&cursors[e], 1);
        rows_token[pos] = t;
        rows_w[pos] = tok_w[pair];
    }
    pos = __shfl(pos, 0, 64);
    const float4* src = (const float4*)(x + (size_t)t * HD);
    bf16_t* dst = Xg + (size_t)pos * HD;
    #pragma unroll
    for (int i = 0; i < HD / 256; ++i) {
        float4 v = src[lane + 64 * i];
        int base = (lane + 64 * i) * 4;
        bf16x4 o;
        o[0] = (bf16_t)v.x; o[1] = (bf16_t)v.y;
        o[2] = (bf16_t)v.z; o[3] = (bf16_t)v.w;
        *(bf16x4*)(dst + base) = o;
    }
}

// ---------------------------------------------------------------------------
// Shared GEMM mainloop: C[128x128] += A[128xK] * B^T[128xK] (both bf16,
// K-contiguous). 4 waves, each 64x64 via 4x4 grid of 16x16x32 MFMAs.
// MFMA layouts (verified gfx950): A[m=lane&15][k=quad*8+j],
// B[k=quad*8+j][n=lane&15], D[row=quad*4+r][col=lane&15].
// ---------------------------------------------------------------------------
template<int KDIM>
__device__ __forceinline__ void gemm_tile(
    const bf16_t* __restrict__ aG,   // 128 rows, stride KDIM
    const bf16_t* __restrict__ bG,   // 128 rows (N-dim), stride KDIM
    bf16_t As[BM][LDS_STRIDE], bf16_t Bs[BN][LDS_STRIDE],
    floatx4 acc[4][4])
{
    const int tid = threadIdx.x;
    const int lane = tid & 63;
    const int wave = tid >> 6;
    const int quad = lane >> 4;
    const int l16 = lane & 15;
    const int wm = (wave & 1) * 64;
    const int wn = (wave >> 1) * 64;
    const int r0 = tid >> 3;         // 0..31
    const int c0 = (tid & 7) * 8;    // 0..56

    for (int k0 = 0; k0 < KDIM; k0 += BK) {
        #pragma unroll
        for (int p = 0; p < 4; ++p) {
            int r = p * 32 + r0;
            *(bf16x8*)(&As[r][c0]) = *(const bf16x8*)(aG + (size_t)r * KDIM + k0 + c0);
            *(bf16x8*)(&Bs[r][c0]) = *(const bf16x8*)(bG + (size_t)r * KDIM + k0 + c0);
        }
        __syncthreads();
        #pragma unroll
        for (int kk = 0; kk < BK; kk += 32) {
            bf16x8 af[4], bfr[4];
            #pragma unroll
            for (int i = 0; i < 4; ++i)
                af[i] = *(const bf16x8*)(&As[wm + i * 16 + l16][kk + quad * 8]);
            #pragma unroll
            for (int i = 0; i < 4; ++i)
                bfr[i] = *(const bf16x8*)(&Bs[wn + i * 16 + l16][kk + quad * 8]);
            #pragma unroll
            for (int i = 0; i < 4; ++i)
                #pragma unroll
                for (int j = 0; j < 4; ++j)
                    acc[i][j] = __builtin_amdgcn_mfma_f32_16x16x32_bf16(
                        af[i], bfr[j], acc[i][j], 0, 0, 0);
        }
        __syncthreads();
    }
}

// ---------------------------------------------------------------------------
// FFN1: Hb = gelu(Xg @ w1t^T + b1), bf16 out. grid (FD/BN, RCAP_M_TILES, NE)
// ---------------------------------------------------------------------------
__global__ __launch_bounds__(256) void ffn1_kernel(
    const bf16_t* __restrict__ Xg, const bf16_t* __restrict__ w1t,
    const float* __restrict__ b1, bf16_t* __restrict__ Hb,
    const int* __restrict__ counts, const int* __restrict__ offsets)
{
    const int e = blockIdx.z;
    const int cnt = counts[e];
    const int mtile = blockIdx.y;
    if (mtile * BM >= cnt) return;
    const int m_base = offsets[e] + mtile * BM;
    const int n_base = blockIdx.x * BN;

    __shared__ bf16_t As[BM][LDS_STRIDE];
    __shared__ bf16_t Bs[BN][LDS_STRIDE];
    floatx4 acc[4][4] = {};

    gemm_tile<HD>(Xg + (size_t)m_base * HD,
                  w1t + ((size_t)e * FD + n_base) * HD, As, Bs, acc);

    const int lane = threadIdx.x & 63;
    const int wave = threadIdx.x >> 6;
    const int quad = lane >> 4;
    const int l16 = lane & 15;
    const int wm = (wave & 1) * 64;
    const int wn = (wave >> 1) * 64;
    #pragma unroll
    for (int i = 0; i < 4; ++i) {
        int rl = wm + i * 16 + quad * 4;
        #pragma unroll
        for (int j = 0; j < 4; ++j) {
            int col = n_base + wn + j * 16 + l16;
            float bias = b1[e * FD + col];
            #pragma unroll
            for (int r = 0; r < 4; ++r) {
                float v = acc[i][j][r] + bias;
                Hb[(size_t)(m_base + rl + r) * FD + col] = (bf16_t)gelu_tanh(v);
            }
        }
    }
}

// ---------------------------------------------------------------------------
// FFN2: out[token] += w * (Hb @ w2t^T + b2). grid (HD/BN, RCAP_M_TILES, NE)
// ---------------------------------------------------------------------------
__global__ __launch_bounds__(256) void ffn2_kernel(
    const bf16_t* __restrict__ Hb, const bf16_t* __restrict__ w2t,
    const float* __restrict__ b2, float* __restrict__ out,
    const int* __restrict__ counts, const int* __restrict__ offsets,
    const int* __restrict__ rows_token, const float* __restrict__ rows_w)
{
    const int e = blockIdx.z;
    const int cnt = counts[e];
    const int mtile = blockIdx.y;
    if (mtile * BM >= cnt) return;
    const int m_base = offsets[e] + mtile * BM;
    const int n_base = blockIdx.x * BN;

    __shared__ bf16_t As[BM][LDS_STRIDE];
    __shared__ bf16_t Bs[BN][LDS_STRIDE];
    floatx4 acc[4][4] = {};

    gemm_tile<FD>(Hb + (size_t)m_base * FD,
                  w2t + ((size_t)e * HD + n_base) * FD, As, Bs, acc);

    const int lane = threadIdx.x & 63;
    const int wave = threadIdx.x >> 6;
    const int quad = lane >> 4;
    const int l16 = lane & 15;
    const int wm = (wave & 1) * 64;
    const int wn = (wave >> 1) * 64;
    const int loc_base = mtile * BM;   // m_base - offsets[e]
    #pragma unroll
    for (int i = 0; i < 4; ++i) {
        int rl = wm + i * 16 + quad * 4;
        #pragma unroll
        for (int j = 0; j < 4; ++j) {
            int col = n_base + wn + j * 16 + l16;
            float bias = b2[e * HD + col];
            #pragma unroll
            for (int r = 0; r < 4; ++r) {
                if (loc_base + rl + r < cnt) {
                    int gr = m_base + rl + r;
                    int token = rows_token[gr];
                    float wgt = rows_w[gr];
                    float v = acc[i][j][r] + bias;
                    atomicAdd(&out[(size_t)token * HD + col], wgt * v);
                }
            }
        }
    }
}

// ---------------------------------------------------------------------------
extern "C" void kernel_launch(void* const* d_in, const int* in_sizes, int n_in,
                              void* d_out, int out_size, void* d_ws, size_t ws_size,
                              hipStream_t stream)
{
    (void)in_sizes; (void)n_in; (void)ws_size;
    const float* x  = (const float*)d_in[0];   // [T, H]
    const float* w1 = (const float*)d_in[1];   // [E, H, F]
    const float* b1 = (const float*)d_in[2];   // [E, F]
    const float* w2 = (const float*)d_in[3];   // [E, F, H]
    const float* b2 = (const float*)d_in[4];   // [E, H]
    const float* rw = (const float*)d_in[5];   // [H, E]
    const float* rb = (const float*)d_in[6];   // [E]
    float* out = (float*)d_out;

    // Workspace carve-up (~313 MB total)
    char* ws = (char*)d_ws;
    size_t off = 0;
    auto alloc = [&](size_t bytes) -> void* {
        void* p = ws + off;
        off = (off + bytes + 255) & ~(size_t)255;
        return p;
    };
    int*    counts     = (int*)alloc(NE * sizeof(int));
    int*    cursors    = (int*)alloc(NE * sizeof(int));
    int*    offsets    = (int*)alloc(NE * sizeof(int));
    int*    tok_e      = (int*)alloc((size_t)T_TOK * 2 * sizeof(int));
    float*  tok_w      = (float*)alloc((size_t)T_TOK * 2 * sizeof(float));
    int*    rows_token = (int*)alloc((size_t)RCAP * sizeof(int));
    float*  rows_w     = (float*)alloc((size_t)RCAP * sizeof(float));
    bf16_t* Xg         = (bf16_t*)alloc((size_t)RCAP * HD * sizeof(bf16_t));
    bf16_t* Hb         = (bf16_t*)alloc((size_t)RCAP * FD * sizeof(bf16_t));
    bf16_t* w1t        = (bf16_t*)alloc((size_t)NE * FD * HD * sizeof(bf16_t));
    bf16_t* w2t        = (bf16_t*)alloc((size_t)NE * HD * FD * sizeof(bf16_t));

    hipMemsetAsync(counts, 0, NE * sizeof(int), stream);
    hipMemsetAsync(out, 0, (size_t)out_size * sizeof(float), stream);

    // 1. weight transpose+convert (bf16, [N][K] layout for both GEMMs)
    transpose_conv_kernel<<<dim3(FD / 32, HD / 32, NE), 256, 0, stream>>>(w1, w1t, HD, FD);
    transpose_conv_kernel<<<dim3(HD / 32, FD / 32, NE), 256, 0, stream>>>(w2, w2t, FD, HD);

    // 2. router
    router_kernel<<<dim3(T_TOK / 4), 256, 0, stream>>>(x, rw, rb, tok_e, tok_w, counts);

    // 3. offsets
    offsets_kernel<<<dim3(1), 64, 0, stream>>>(counts, offsets, cursors);

    // 4. gather
    gather_kernel<<<dim3(T_TOK * 2 / 4), 256, 0, stream>>>(
        x, tok_e, tok_w, cursors, Xg, rows_token, rows_w);

    // 5. FFN1 (+gelu) — worst-case M tiles = 8192/128 = 64, early-exit on counts
    ffn1_kernel<<<dim3(FD / BN, T_TOK / BM, NE), 256, 0, stream>>>(
        Xg, w1t, b1, Hb, counts, offsets);

    // 6. FFN2 (+bias, weighted scatter-add)
    ffn2_kernel<<<dim3(HD / BN, T_TOK / BM, NE), 256, 0, stream>>>(
        Hb, w2t, b2, out, counts, offsets, rows_token, rows_w);
}